// Round 11
// baseline (447.479 us; speedup 1.0000x reference)
//
#include <hip/hip_runtime.h>
#include <hip/hip_bf16.h>
#include <math.h>

#define N_NODES 100000
#define N_EDGES 1600000
#define D 128
#define NEG 0.2f
#define LN_EPS 1e-5f

#define GEMM_BLOCKS ((N_NODES + 63) / 64)       // 1563 (64 rows/block)
#define PLACE_BLOCKS ((N_EDGES + 1023) / 1024)  // 1563 (1024 edges/block, 4/thread)
#define AGG_BLOCKS (N_NODES / 16)               // 6250 (16 nodes/block, 16 lanes/node)

typedef __attribute__((ext_vector_type(8))) short bf16x8;
typedef __attribute__((ext_vector_type(4))) float f32x4;

__device__ __forceinline__ float lrelu(float v){ return fmaxf(v, NEG * v); }
__device__ __forceinline__ float gelu_exact(float v){ return 0.5f * v * (1.0f + erff(v * 0.7071067811865476f)); }
__device__ __forceinline__ float wave_sum(float v){
#pragma unroll
  for (int o = 32; o; o >>= 1) v += __shfl_xor(v, o, 64);
  return v;
}
__device__ __forceinline__ unsigned short f2bf(float f){
  __hip_bfloat16 h = __float2bfloat16(f);            // RNE
  return *(unsigned short*)&h;
}
// bf16 pair unpack: low 16 bits = even col, high = odd col
__device__ __forceinline__ float bf_lo(unsigned u){ return __uint_as_float(u << 16); }
__device__ __forceinline__ float bf_hi(unsigned u){ return __uint_as_float(u & 0xFFFF0000u); }

// csr entry packing: src (17b) << 15 | w quantized to 15b in [0,1).
// Quantization error <=1.5e-5 on a logit term -- negligible vs bf16 h rounding.
#define W_SCALE 32767.0f
#define W_INV   (1.0f / 32767.0f)
__device__ __forceinline__ unsigned pack_e(int src, float w){
  unsigned q = (unsigned)__float2uint_rn(w * W_SCALE);
  return ((unsigned)src << 15) | q;
}

// ---------------- prep: W -> B-fragment bf16 layout + c_e ----------------
// Parallel over 16 blocks. Wfrag slot = ((l*8+ct)*4+kc)*64+lane, 8 bf16 each:
//   Wfrag[slot][j] = bf16( W[l][ kc*32 + (lane>>4)*8 + j ][ ct*16 + (lane&15) ] )
__global__ __launch_bounds__(256) void k_prep(const float* __restrict__ W,
                                              unsigned short* __restrict__ wfrag,
                                              const float* __restrict__ lew,
                                              const float* __restrict__ ae,
                                              float* __restrict__ c_e){
  if (blockIdx.x == 0 && threadIdx.x < 128){
    int l = threadIdx.x >> 6;
    int lane = threadIdx.x & 63;
    const float* a = lew + l * D;
    const float* b = ae + l * D;
    float v = a[lane] * b[lane] + a[64 + lane] * b[64 + lane];
    v = wave_sum(v);
    if (lane == 0) c_e[l] = v;
  }
  int slot = blockIdx.x * 256 + threadIdx.x;         // 4096 slots over 16 blocks
  int lane = slot & 63;
  int kc   = (slot >> 6) & 3;
  int ct   = (slot >> 8) & 7;
  int l    = (slot >> 11) & 1;
  int quad = lane >> 4, n = (lane & 15) + ct * 16;
  const float* Wl = W + l * D * D;
  bf16x8 v;
#pragma unroll
  for (int j = 0; j < 8; j++){
    int k = kc * 32 + quad * 8 + j;
    v[j] = (short)f2bf(Wl[k * D + n]);
  }
  *(bf16x8*)(wfrag + (size_t)slot * 8) = v;
}

// ---------------- MFMA GEMM body (64-row blocks) ----------------
// h[64rows,128](bf16) = A[64rows,128] @ W ; alpha_s/d fused.
// Wave = 16-row strip; 8 col-tiles x 4 k-chunks of mfma_f32_16x16x32_bf16.
// A: lane holds A[m=lane&15][k=quad*8+j].  C/D: col=lane&15, row=quad*4+reg.
template<bool ABF>
__device__ __forceinline__ void gemm_mfma(int gb,
                                          const void* __restrict__ xin_,
                                          const unsigned short* __restrict__ wfrag_l,
                                          const float* __restrict__ att_s,
                                          const float* __restrict__ att_d,
                                          unsigned short* __restrict__ hb,
                                          float* __restrict__ alpha_s,
                                          float* __restrict__ alpha_d){
  __shared__ __align__(16) unsigned short hstage[64 * 136]; // 272B row stride (bank-safe)
  int tid = threadIdx.x;
  int wv = tid >> 6, lane = tid & 63;
  int quad = lane >> 4, c15 = lane & 15;
  int row0 = gb * 64 + wv * 16;

  int arow = min(row0 + c15, N_NODES - 1);
  bf16x8 a[4];
  if constexpr (ABF){
    const unsigned short* xr = (const unsigned short*)xin_ + (size_t)arow * D;
#pragma unroll
    for (int kc = 0; kc < 4; kc++)
      a[kc] = *(const bf16x8*)(xr + kc * 32 + quad * 8);
  } else {
    const float* xr = (const float*)xin_ + (size_t)arow * D;
#pragma unroll
    for (int kc = 0; kc < 4; kc++){
      float4 p = *(const float4*)(xr + kc * 32 + quad * 8);
      float4 q = *(const float4*)(xr + kc * 32 + quad * 8 + 4);
      bf16x8 t;
      t[0] = (short)f2bf(p.x); t[1] = (short)f2bf(p.y);
      t[2] = (short)f2bf(p.z); t[3] = (short)f2bf(p.w);
      t[4] = (short)f2bf(q.x); t[5] = (short)f2bf(q.y);
      t[6] = (short)f2bf(q.z); t[7] = (short)f2bf(q.w);
      a[kc] = t;
    }
  }

  f32x4 acc[8];
#pragma unroll
  for (int ct = 0; ct < 8; ct++) acc[ct] = (f32x4){0.f, 0.f, 0.f, 0.f};

#pragma unroll
  for (int ct = 0; ct < 8; ct++){
#pragma unroll
    for (int kc = 0; kc < 4; kc++){
      bf16x8 b = *(const bf16x8*)(wfrag_l + ((size_t)(ct * 4 + kc) * 64 + lane) * 8);
      acc[ct] = __builtin_amdgcn_mfma_f32_16x16x32_bf16(a[kc], b, acc[ct], 0, 0, 0);
    }
  }

  float attsv[8], attdv[8];
#pragma unroll
  for (int ct = 0; ct < 8; ct++){
    attsv[ct] = att_s[ct * 16 + c15];
    attdv[ct] = att_d[ct * 16 + c15];
  }
#pragma unroll
  for (int reg = 0; reg < 4; reg++){
    float ps = 0.f, pd = 0.f;
#pragma unroll
    for (int ct = 0; ct < 8; ct++){
      ps += acc[ct][reg] * attsv[ct];
      pd += acc[ct][reg] * attdv[ct];
    }
#pragma unroll
    for (int o = 8; o; o >>= 1){
      ps += __shfl_xor(ps, o, 64);
      pd += __shfl_xor(pd, o, 64);
    }
    int row = row0 + quad * 4 + reg;
    if (c15 == reg && row < N_NODES){ alpha_s[row] = ps; alpha_d[row] = pd; }
  }

#pragma unroll
  for (int ct = 0; ct < 8; ct++)
#pragma unroll
    for (int reg = 0; reg < 4; reg++)
      hstage[(wv * 16 + quad * 4 + reg) * 136 + ct * 16 + c15] = f2bf(acc[ct][reg]);
  __syncthreads();
#pragma unroll
  for (int i = 0; i < 4; i++){
    int flat = i * 256 + tid;                        // 1024 uint4 = 64 rows x 16
    int row = flat >> 4, c = flat & 15;
    int grow = gb * 64 + row;
    if (grow < N_NODES)
      *(uint4*)(hb + (size_t)grow * D + c * 8) = *(const uint4*)(hstage + row * 136 + c * 8);
  }
}

// ---------------- fused: layer-1 GEMM + bucketed CSR build ----------------
// Placement blocks FIRST; GEMM backfills. Counters padded (cstride=16 ints =
// one per 64B line). csr entries packed to 4B -> a node's 16-slot chunk is
// exactly one 64B line.
__global__ __launch_bounds__(256, 4) void k_gemm1_place(const float* __restrict__ xin,
                                                        const unsigned short* __restrict__ wfrag,
                                                        const float* __restrict__ att_s,
                                                        const float* __restrict__ att_d,
                                                        unsigned short* __restrict__ hb,
                                                        float* __restrict__ alpha_s,
                                                        float* __restrict__ alpha_d,
                                                        const int* __restrict__ ei,
                                                        const float* __restrict__ ew,
                                                        int* __restrict__ counter, int cstride,
                                                        unsigned* __restrict__ csr, int cap){
  if (blockIdx.x >= PLACE_BLOCKS){
    gemm_mfma<false>(blockIdx.x - PLACE_BLOCKS, xin, wfrag, att_s, att_d, hb, alpha_s, alpha_d);
  } else {
    int pb = blockIdx.x;
    int e0 = pb * 1024 + threadIdx.x;
    int ss[4], dd[4], pp[4]; float wwv[4]; bool va[4];
#pragma unroll
    for (int i = 0; i < 4; i++){
      int e = e0 + i * 256;
      va[i] = e < N_EDGES;
      ss[i] = va[i] ? ei[e] : 0;
      dd[i] = va[i] ? ei[N_EDGES + e] : 0;
      wwv[i] = va[i] ? ew[e] : 0.f;
    }
#pragma unroll
    for (int i = 0; i < 4; i++) if (va[i]) pp[i] = atomicAdd(&counter[dd[i] * cstride], 1);
#pragma unroll
    for (int i = 0; i < 4; i++)
      if (va[i] && pp[i] < cap)
        csr[(size_t)dd[i] * cap + pp[i]] = pack_e(ss[i], wwv[i]);
  }
}

// layer-2 GEMM standalone (fallback path; A input bf16)
__global__ __launch_bounds__(256, 4) void k_gemm_alpha(const unsigned short* __restrict__ xin,
                                                       const unsigned short* __restrict__ wfrag,
                                                       const float* __restrict__ att_s,
                                                       const float* __restrict__ att_d,
                                                       unsigned short* __restrict__ hb,
                                                       float* __restrict__ alpha_s,
                                                       float* __restrict__ alpha_d){
  gemm_mfma<true>(blockIdx.x, xin, wfrag, att_s, att_d, hb, alpha_s, alpha_d);
}

#define GATHER_ACC(PV, SV, IDX)                                              \
  {                                                                          \
    float pi = __shfl((PV), qbase + (IDX), 64);                              \
    int   si = __shfl((SV), qbase + (IDX), 64);                              \
    uint4 u = *((const uint4*)(hb + (size_t)si * D) + cg);                   \
    acc[0] += pi * bf_lo(u.x); acc[1] += pi * bf_hi(u.x);                    \
    acc[2] += pi * bf_lo(u.y); acc[3] += pi * bf_hi(u.y);                    \
    acc[4] += pi * bf_lo(u.z); acc[5] += pi * bf_hi(u.z);                    \
    acc[6] += pi * bf_lo(u.w); acc[7] += pi * bf_hi(u.w);                    \
  }

// ---------------- agg core: 16 lanes per node (round-5 measured-best) ------
// Fast path: slots 0..31 with ONE dependent csr->alpha->exp round; when any
// group in the wave has dg>16, a STRAIGHT-LINE 32-gather body (no branch
// between chunks) lets the compiler issue all 32 row loads back-to-back --
// 2x memory-level parallelism per wave at FIXED occupancy (rounds 7/8 showed
// adding waves inflates the L2 working set; adding per-wave MLP does not:
// ~6.7 waves x 32 rows x 256B = 0.44MB << 4MB per-XCD L2).
template<bool LN>
__device__ __forceinline__ void agg_core(const unsigned short* __restrict__ hb,
                                         const float* __restrict__ alpha_s,
                                         const float* __restrict__ alpha_d,
                                         const int* __restrict__ counter, int cstride,
                                         const unsigned* __restrict__ csr, int cap,
                                         float c,
                                         const float* __restrict__ bias_l,
                                         const float* __restrict__ xres,
                                         const float* __restrict__ gamma,
                                         const float* __restrict__ beta,
                                         int n, int cg, int qbase,
                                         float o[8]){
  int deg = counter[n * cstride];
  int dg = min(deg, cap);
  size_t rs = (size_t)n * cap;
  float ad = alpha_d[n];
  float as_n = alpha_s[n];

  uint4 u_self = *((const uint4*)(hb + (size_t)n * D) + cg);
  float4 b_lo = *(const float4*)(bias_l + cg * 8);
  float4 b_hi = *(const float4*)(bias_l + cg * 8 + 4);
  float4 xr_lo, xr_hi, g_lo, g_hi, bt_lo, bt_hi;
  if constexpr (LN){
    const float* xr = xres + (size_t)n * D + cg * 8;
    xr_lo = *(const float4*)(xr);
    xr_hi = *(const float4*)(xr + 4);
    g_lo  = *(const float4*)(gamma + cg * 8);
    g_hi  = *(const float4*)(gamma + cg * 8 + 4);
    bt_lo = *(const float4*)(beta + cg * 8);
    bt_hi = *(const float4*)(beta + cg * 8 + 4);
  }

  float z = 0.f, wsum = 0.f;
  float acc[8];
#pragma unroll
  for (int k = 0; k < 8; k++) acc[k] = 0.f;

  // ---- fused first-32 fast path ----
  {
    float p = 0.f, p2 = 0.f; int s = n, s2 = n;
    if (cg < dg){
      unsigned e1 = csr[rs + cg];
      s = (int)(e1 >> 15);
      float w = (float)(e1 & 0x7FFFu) * W_INV;
      wsum += w;
      p = __expf(lrelu(alpha_s[s] + ad + c * w));
    }
    if (16 + cg < dg){
      unsigned e2 = csr[rs + 16 + cg];
      s2 = (int)(e2 >> 15);
      float w = (float)(e2 & 0x7FFFu) * W_INV;
      wsum += w;
      p2 = __expf(lrelu(alpha_s[s2] + ad + c * w));
    }
    z += p + p2;
    if (__any(dg > 16)){
      // straight-line 32-gather body: all loads can be in flight together
#pragma unroll
      for (int i = 0; i < 16; i++) GATHER_ACC(p, s, i)
#pragma unroll
      for (int i = 0; i < 16; i++) GATHER_ACC(p2, s2, i)
    } else {
#pragma unroll
      for (int i = 0; i < 16; i++) GATHER_ACC(p, s, i)
    }
  }
  // ---- rare tail (deg > 32) ----
  for (int base = 32; base < dg; base += 16){
    int j = base + cg;
    float p = 0.f; int s = n;
    if (j < dg){
      unsigned e1 = csr[rs + j];
      s = (int)(e1 >> 15);
      float w = (float)(e1 & 0x7FFFu) * W_INV;
      wsum += w;
      p = __expf(lrelu(alpha_s[s] + ad + c * w));
    }
    z += p;
#pragma unroll
    for (int i = 0; i < 16; i++) GATHER_ACC(p, s, i)
  }
#pragma unroll
  for (int ofs = 8; ofs; ofs >>= 1){
    z += __shfl_xor(z, ofs, 64);
    wsum += __shfl_xor(wsum, ofs, 64);
  }

  float lw = wsum / fmaxf((float)deg, 1.0f);
  float ps = __expf(lrelu(as_n + ad + c * lw));
  z += ps;
  acc[0] += ps * bf_lo(u_self.x); acc[1] += ps * bf_hi(u_self.x);
  acc[2] += ps * bf_lo(u_self.y); acc[3] += ps * bf_hi(u_self.y);
  acc[4] += ps * bf_lo(u_self.z); acc[5] += ps * bf_hi(u_self.z);
  acc[6] += ps * bf_lo(u_self.w); acc[7] += ps * bf_hi(u_self.w);

  float inv = 1.0f / z;
  float bv[8] = {b_lo.x, b_lo.y, b_lo.z, b_lo.w, b_hi.x, b_hi.y, b_hi.z, b_hi.w};
#pragma unroll
  for (int k = 0; k < 8; k++) o[k] = gelu_exact(acc[k] * inv + bv[k]);

  if constexpr (LN){
    float xrv[8] = {xr_lo.x, xr_lo.y, xr_lo.z, xr_lo.w, xr_hi.x, xr_hi.y, xr_hi.z, xr_hi.w};
    float s1 = 0.f;
#pragma unroll
    for (int k = 0; k < 8; k++){ o[k] += xrv[k]; s1 += o[k]; }
#pragma unroll
    for (int ofs = 8; ofs; ofs >>= 1) s1 += __shfl_xor(s1, ofs, 64);
    float mu = s1 * (1.0f / D);
    float s2 = 0.f;
#pragma unroll
    for (int k = 0; k < 8; k++){ o[k] -= mu; s2 += o[k] * o[k]; }
#pragma unroll
    for (int ofs = 8; ofs; ofs >>= 1) s2 += __shfl_xor(s2, ofs, 64);
    float rinv = rsqrtf(s2 * (1.0f / D) + LN_EPS);
    float gv[8]  = {g_lo.x, g_lo.y, g_lo.z, g_lo.w, g_hi.x, g_hi.y, g_hi.z, g_hi.w};
    float btv[8] = {bt_lo.x, bt_lo.y, bt_lo.z, bt_lo.w, bt_hi.x, bt_hi.y, bt_hi.z, bt_hi.w};
#pragma unroll
    for (int k = 0; k < 8; k++) o[k] = o[k] * rinv * gv[k] + btv[k];
  }
}

// ---------------- layer-1 agg + FUSED layer-2 GEMM (16 nodes/block) --------
__global__ __launch_bounds__(256) void k_agg1_fused(const unsigned short* __restrict__ hb,
                                                    const float* __restrict__ alpha_s,
                                                    const float* __restrict__ alpha_d,
                                                    const int* __restrict__ counter, int cstride,
                                                    const unsigned* __restrict__ csr, int cap,
                                                    const float* __restrict__ c_e,
                                                    const float* __restrict__ bias,
                                                    const unsigned short* __restrict__ wfrag2,
                                                    const float* __restrict__ att_s2,
                                                    const float* __restrict__ att_d2,
                                                    unsigned short* __restrict__ hb2,
                                                    float* __restrict__ alpha2_s,
                                                    float* __restrict__ alpha2_d){
  __shared__ __align__(16) unsigned short astage[16 * 136];  // A tile, reused for h2
  __shared__ float apart_s[16], apart_d[16];
  int tid = threadIdx.x;
  int lane = tid & 63;
  int cg = lane & 15;
  int qbase = lane & 48;
  int n = blockIdx.x * 16 + (tid >> 4);

  float o[8];
  agg_core<false>(hb, alpha_s, alpha_d, counter, cstride, csr, cap, c_e[0],
                  bias, nullptr, nullptr, nullptr, n, cg, qbase, o);

  // stage bf16 GELU tile: row = tid>>4 (node), cols cg*8..cg*8+7
  unsigned short ob[8];
#pragma unroll
  for (int k = 0; k < 8; k++) ob[k] = f2bf(o[k]);
  *(uint4*)(astage + (tid >> 4) * 136 + cg * 8) = *(const uint4*)ob;
  if (tid < 16){ apart_s[tid] = 0.f; apart_d[tid] = 0.f; }
  __syncthreads();

  // ---- GEMM phase: wave wv computes col-tiles {2wv, 2wv+1} for all 16 rows
  int wv = tid >> 6;
  int quad = lane >> 4, c15 = lane & 15;
  bf16x8 a[4];
#pragma unroll
  for (int kc = 0; kc < 4; kc++)
    a[kc] = *(const bf16x8*)(astage + c15 * 136 + kc * 32 + quad * 8);

  f32x4 acc2[2];
  float attsv[2], attdv[2];
#pragma unroll
  for (int t = 0; t < 2; t++){
    int ct = wv * 2 + t;
    acc2[t] = (f32x4){0.f, 0.f, 0.f, 0.f};
#pragma unroll
    for (int kc = 0; kc < 4; kc++){
      bf16x8 b = *(const bf16x8*)(wfrag2 + ((size_t)(ct * 4 + kc) * 64 + lane) * 8);
      acc2[t] = __builtin_amdgcn_mfma_f32_16x16x32_bf16(a[kc], b, acc2[t], 0, 0, 0);
    }
    attsv[t] = att_s2[ct * 16 + c15];
    attdv[t] = att_d2[ct * 16 + c15];
  }

  // alpha2 partials (this wave's 2 col-tiles), reduce within 16-lane group
#pragma unroll
  for (int reg = 0; reg < 4; reg++){
    float ps = acc2[0][reg] * attsv[0] + acc2[1][reg] * attsv[1];
    float pd = acc2[0][reg] * attdv[0] + acc2[1][reg] * attdv[1];
#pragma unroll
    for (int ofs = 8; ofs; ofs >>= 1){
      ps += __shfl_xor(ps, ofs, 64);
      pd += __shfl_xor(pd, ofs, 64);
    }
    if (c15 == reg){
      atomicAdd(&apart_s[quad * 4 + reg], ps);
      atomicAdd(&apart_d[quad * 4 + reg], pd);
    }
  }
  __syncthreads();                      // all a[] reads done -> astage reusable

  // stage h2: row = quad*4+reg, col = ct*16+c15
#pragma unroll
  for (int t = 0; t < 2; t++){
    int ct = wv * 2 + t;
#pragma unroll
    for (int reg = 0; reg < 4; reg++)
      astage[(quad * 4 + reg) * 136 + ct * 16 + c15] = f2bf(acc2[t][reg]);
  }
  __syncthreads();

  {
    int row = tid >> 4, ccol = tid & 15;             // 256 uint4 = 16 rows x 16
    int grow = blockIdx.x * 16 + row;
    *(uint4*)(hb2 + (size_t)grow * D + ccol * 8) = *(const uint4*)(astage + row * 136 + ccol * 8);
  }
  if (tid < 16){
    int grow = blockIdx.x * 16 + tid;
    alpha2_s[grow] = apart_s[tid];
    alpha2_d[grow] = apart_d[tid];
  }
}

// layer-1 agg plain (fallback): writes bf16 row that feeds standalone gemm2
__global__ __launch_bounds__(256) void k_agg1_plain(const unsigned short* __restrict__ hb,
                                                    const float* __restrict__ alpha_s,
                                                    const float* __restrict__ alpha_d,
                                                    const int* __restrict__ counter, int cstride,
                                                    const unsigned* __restrict__ csr, int cap,
                                                    const float* __restrict__ c_e,
                                                    const float* __restrict__ bias,
                                                    unsigned short* __restrict__ outp_bf){
  int tid = threadIdx.x;
  int lane = tid & 63;
  int cg = lane & 15;
  int qbase = lane & 48;
  int n = blockIdx.x * 16 + (tid >> 4);
  float o[8];
  agg_core<false>(hb, alpha_s, alpha_d, counter, cstride, csr, cap, c_e[0],
                  bias, nullptr, nullptr, nullptr, n, cg, qbase, o);
  unsigned short ob[8];
#pragma unroll
  for (int k = 0; k < 8; k++) ob[k] = f2bf(o[k]);
  *(uint4*)(outp_bf + (size_t)n * D + cg * 8) = *(const uint4*)ob;
}

// layer-2 agg: residual + LayerNorm, fp32 out
__global__ __launch_bounds__(256) void k_agg2(const unsigned short* __restrict__ hb,
                                              const float* __restrict__ alpha_s,
                                              const float* __restrict__ alpha_d,
                                              const int* __restrict__ counter, int cstride,
                                              const unsigned* __restrict__ csr, int cap,
                                              const float* __restrict__ c_e,
                                              const float* __restrict__ bias,
                                              const float* __restrict__ xres,
                                              const float* __restrict__ gamma,
                                              const float* __restrict__ beta,
                                              float* __restrict__ outp){
  int tid = threadIdx.x;
  int lane = tid & 63;
  int cg = lane & 15;
  int qbase = lane & 48;
  int n = blockIdx.x * 16 + (tid >> 4);
  float o[8];
  agg_core<true>(hb, alpha_s, alpha_d, counter, cstride, csr, cap, c_e[1],
                 bias + D, xres, gamma, beta, n, cg, qbase, o);
  float* orow = outp + (size_t)n * D + cg * 8;
  *(float4*)(orow)     = make_float4(o[0], o[1], o[2], o[3]);
  *(float4*)(orow + 4) = make_float4(o[4], o[5], o[6], o[7]);
}

extern "C" void kernel_launch(void* const* d_in, const int* in_sizes, int n_in,
                              void* d_out, int out_size, void* d_ws, size_t ws_size,
                              hipStream_t stream) {
  const float* x     = (const float*)d_in[0];
  const int*   ei    = (const int*)d_in[1];       // [2,E]: src then dst
  const float* ew    = (const float*)d_in[2];
  const float* W     = (const float*)d_in[3];     // [2,128,128]
  const float* att_s = (const float*)d_in[4];
  const float* att_d = (const float*)d_in[5];
  const float* lew   = (const float*)d_in[6];
  const float* ae    = (const float*)d_in[7];
  const float* bias  = (const float*)d_in[8];
  const float* gamma = (const float*)d_in[9];
  const float* beta  = (const float*)d_in[10];
  float* out = (float*)d_out;

  const int N = N_NODES;

  // workspace sizing: counters (padded to 64B/line when space allows) +
  // 4 alpha arrays + c_e + wfrag + csr(N*cap*4, packed) + hb (+ hb2 if fused).
  size_t hbB = (size_t)N * D * 2;
  size_t fixP = ((size_t)(16 * N) + 4 * N + 16) * 4 + 65536;  // padded counters
  size_t fix1 = ((size_t)N + 4 * N + 16) * 4 + 65536;         // stride-1 counters
  int cstride; bool fused; int cap;
  if      (ws_size >= fixP + (size_t)N * 64 * 4 + 2 * hbB){ cstride = 16; fused = true;  cap = 64; }
  else if (ws_size >= fixP + (size_t)N * 48 * 4 + 2 * hbB){ cstride = 16; fused = true;  cap = 48; }
  else if (ws_size >= fix1 + (size_t)N * 64 * 4 + 2 * hbB){ cstride = 1;  fused = true;  cap = 64; }
  else if (ws_size >= fix1 + (size_t)N * 64 * 4 + hbB)    { cstride = 1;  fused = false; cap = 64; }
  else                                                     { cstride = 1;  fused = false; cap = 48; }

  // ---- workspace carve (all offsets 16B-aligned) ----
  int*   counter  = (int*)d_ws;                        // N*cstride
  float* alpha_s  = (float*)(counter + (size_t)N * cstride); // N
  float* alpha_d  = alpha_s + N;                       // N
  float* alpha2_s = alpha_d + N;                       // N
  float* alpha2_d = alpha2_s + N;                      // N
  float* c_e      = alpha2_d + N;                      // 2 (+14 pad)
  unsigned short* wfrag = (unsigned short*)(c_e + 16); // 32768 shorts (64 KB)
  unsigned* csr   = (unsigned*)(wfrag + 32768);        // N*cap packed {src,w}
  unsigned short* hb  = (unsigned short*)(csr + (size_t)N * cap); // N*D bf16 (layer-1 h)
  unsigned short* hb2 = hb + (size_t)N * D;            // N*D bf16 (layer-2 h, fused only)

  hipMemsetAsync(counter, 0, (size_t)N * cstride * sizeof(int), stream);
  k_prep<<<16, 256, 0, stream>>>(W, wfrag, lew, ae, c_e);

  // ---- layer-1 GEMM fused with CSR build ----
  k_gemm1_place<<<GEMM_BLOCKS + PLACE_BLOCKS, 256, 0, stream>>>(
      x, wfrag, att_s, att_d, hb, alpha_s, alpha_d, ei, ew, counter, cstride, csr, cap);

  if (fused){
    // layer-1 agg + layer-2 GEMM in one kernel
    k_agg1_fused<<<AGG_BLOCKS, 256, 0, stream>>>(
        hb, alpha_s, alpha_d, counter, cstride, csr, cap, c_e, bias,
        wfrag + 16384, att_s + D, att_d + D, hb2, alpha2_s, alpha2_d);
    k_agg2<<<AGG_BLOCKS, 256, 0, stream>>>(
        hb2, alpha2_s, alpha2_d, counter, cstride, csr, cap, c_e, bias, x, gamma, beta, out);
  } else {
    // fallback: layer-1 bf16 intermediate lives in d_out (consumed before agg2 overwrites)
    unsigned short* h1b = (unsigned short*)d_out;
    k_agg1_plain<<<AGG_BLOCKS, 256, 0, stream>>>(
        hb, alpha_s, alpha_d, counter, cstride, csr, cap, c_e, bias, h1b);
    k_gemm_alpha<<<GEMM_BLOCKS, 256, 0, stream>>>(
        h1b, wfrag + 16384, att_s + D, att_d + D, hb, alpha_s, alpha_d);
    k_agg2<<<AGG_BLOCKS, 256, 0, stream>>>(
        hb, alpha_s, alpha_d, counter, cstride, csr, cap, c_e, bias, x, gamma, beta, out);
  }
}

// Round 12
// 421.003 us; speedup vs baseline: 1.0629x; 1.0629x over previous
//
#include <hip/hip_runtime.h>
#include <hip/hip_bf16.h>
#include <math.h>

#define N_NODES 100000
#define N_EDGES 1600000
#define D 128
#define NEG 0.2f
#define LN_EPS 1e-5f

#define GEMM_BLOCKS ((N_NODES + 63) / 64)       // 1563 (64 rows/block)
#define PLACE_BLOCKS ((N_EDGES + 1023) / 1024)  // 1563 (1024 edges/block, 4/thread)
#define AGG_BLOCKS (N_NODES / 16)               // 6250 (16 nodes/block, 16 lanes/node)

typedef __attribute__((ext_vector_type(8))) short bf16x8;
typedef __attribute__((ext_vector_type(4))) float f32x4;

__device__ __forceinline__ float lrelu(float v){ return fmaxf(v, NEG * v); }
__device__ __forceinline__ float gelu_exact(float v){ return 0.5f * v * (1.0f + erff(v * 0.7071067811865476f)); }
__device__ __forceinline__ float wave_sum(float v){
#pragma unroll
  for (int o = 32; o; o >>= 1) v += __shfl_xor(v, o, 64);
  return v;
}
__device__ __forceinline__ unsigned short f2bf(float f){
  __hip_bfloat16 h = __float2bfloat16(f);            // RNE
  return *(unsigned short*)&h;
}
// bf16 pair unpack: low 16 bits = even col, high = odd col
__device__ __forceinline__ float bf_lo(unsigned u){ return __uint_as_float(u << 16); }
__device__ __forceinline__ float bf_hi(unsigned u){ return __uint_as_float(u & 0xFFFF0000u); }

// ---------------- prep: W -> B-fragment bf16 layout + c_e ----------------
// Parallel over 16 blocks (cuts stream-serial time ahead of the fused kernel).
// Wfrag slot = ((l*8+ct)*4+kc)*64+lane, 8 bf16 each:
//   Wfrag[slot][j] = bf16( W[l][ kc*32 + (lane>>4)*8 + j ][ ct*16 + (lane&15) ] )
__global__ __launch_bounds__(256) void k_prep(const float* __restrict__ W,
                                              unsigned short* __restrict__ wfrag,
                                              const float* __restrict__ lew,
                                              const float* __restrict__ ae,
                                              float* __restrict__ c_e){
  if (blockIdx.x == 0 && threadIdx.x < 128){
    int l = threadIdx.x >> 6;
    int lane = threadIdx.x & 63;
    const float* a = lew + l * D;
    const float* b = ae + l * D;
    float v = a[lane] * b[lane] + a[64 + lane] * b[64 + lane];
    v = wave_sum(v);
    if (lane == 0) c_e[l] = v;
  }
  int slot = blockIdx.x * 256 + threadIdx.x;         // 4096 slots over 16 blocks
  int lane = slot & 63;
  int kc   = (slot >> 6) & 3;
  int ct   = (slot >> 8) & 7;
  int l    = (slot >> 11) & 1;
  int quad = lane >> 4, n = (lane & 15) + ct * 16;
  const float* Wl = W + l * D * D;
  bf16x8 v;
#pragma unroll
  for (int j = 0; j < 8; j++){
    int k = kc * 32 + quad * 8 + j;
    v[j] = (short)f2bf(Wl[k * D + n]);
  }
  *(bf16x8*)(wfrag + (size_t)slot * 8) = v;
}

// ---------------- MFMA GEMM body (64-row blocks) ----------------
// h[64rows,128](bf16) = A[64rows,128] @ W ; alpha_s/d fused.
// Wave = 16-row strip; 8 col-tiles x 4 k-chunks of mfma_f32_16x16x32_bf16.
// A: lane holds A[m=lane&15][k=quad*8+j].  C/D: col=lane&15, row=quad*4+reg.
template<bool ABF>
__device__ __forceinline__ void gemm_mfma(int gb,
                                          const void* __restrict__ xin_,
                                          const unsigned short* __restrict__ wfrag_l,
                                          const float* __restrict__ att_s,
                                          const float* __restrict__ att_d,
                                          unsigned short* __restrict__ hb,
                                          float* __restrict__ alpha_s,
                                          float* __restrict__ alpha_d){
  __shared__ __align__(16) unsigned short hstage[64 * 136]; // 272B row stride (bank-safe)
  int tid = threadIdx.x;
  int wv = tid >> 6, lane = tid & 63;
  int quad = lane >> 4, c15 = lane & 15;
  int row0 = gb * 64 + wv * 16;

  int arow = min(row0 + c15, N_NODES - 1);
  bf16x8 a[4];
  if constexpr (ABF){
    const unsigned short* xr = (const unsigned short*)xin_ + (size_t)arow * D;
#pragma unroll
    for (int kc = 0; kc < 4; kc++)
      a[kc] = *(const bf16x8*)(xr + kc * 32 + quad * 8);
  } else {
    const float* xr = (const float*)xin_ + (size_t)arow * D;
#pragma unroll
    for (int kc = 0; kc < 4; kc++){
      float4 p = *(const float4*)(xr + kc * 32 + quad * 8);
      float4 q = *(const float4*)(xr + kc * 32 + quad * 8 + 4);
      bf16x8 t;
      t[0] = (short)f2bf(p.x); t[1] = (short)f2bf(p.y);
      t[2] = (short)f2bf(p.z); t[3] = (short)f2bf(p.w);
      t[4] = (short)f2bf(q.x); t[5] = (short)f2bf(q.y);
      t[6] = (short)f2bf(q.z); t[7] = (short)f2bf(q.w);
      a[kc] = t;
    }
  }

  f32x4 acc[8];
#pragma unroll
  for (int ct = 0; ct < 8; ct++) acc[ct] = (f32x4){0.f, 0.f, 0.f, 0.f};

#pragma unroll
  for (int ct = 0; ct < 8; ct++){
#pragma unroll
    for (int kc = 0; kc < 4; kc++){
      bf16x8 b = *(const bf16x8*)(wfrag_l + ((size_t)(ct * 4 + kc) * 64 + lane) * 8);
      acc[ct] = __builtin_amdgcn_mfma_f32_16x16x32_bf16(a[kc], b, acc[ct], 0, 0, 0);
    }
  }

  float attsv[8], attdv[8];
#pragma unroll
  for (int ct = 0; ct < 8; ct++){
    attsv[ct] = att_s[ct * 16 + c15];
    attdv[ct] = att_d[ct * 16 + c15];
  }
#pragma unroll
  for (int reg = 0; reg < 4; reg++){
    float ps = 0.f, pd = 0.f;
#pragma unroll
    for (int ct = 0; ct < 8; ct++){
      ps += acc[ct][reg] * attsv[ct];
      pd += acc[ct][reg] * attdv[ct];
    }
#pragma unroll
    for (int o = 8; o; o >>= 1){
      ps += __shfl_xor(ps, o, 64);
      pd += __shfl_xor(pd, o, 64);
    }
    int row = row0 + quad * 4 + reg;
    if (c15 == reg && row < N_NODES){ alpha_s[row] = ps; alpha_d[row] = pd; }
  }

#pragma unroll
  for (int ct = 0; ct < 8; ct++)
#pragma unroll
    for (int reg = 0; reg < 4; reg++)
      hstage[(wv * 16 + quad * 4 + reg) * 136 + ct * 16 + c15] = f2bf(acc[ct][reg]);
  __syncthreads();
#pragma unroll
  for (int i = 0; i < 4; i++){
    int flat = i * 256 + tid;                        // 1024 uint4 = 64 rows x 16
    int row = flat >> 4, c = flat & 15;
    int grow = gb * 64 + row;
    if (grow < N_NODES)
      *(uint4*)(hb + (size_t)grow * D + c * 8) = *(const uint4*)(hstage + row * 136 + c * 8);
  }
}

// ---------------- fused: layer-1 GEMM + bucketed CSR build ----------------
// Placement blocks FIRST; GEMM backfills. Counters padded (cstride=16 ints =
// one per 64B line) to cut line-level RMW serialization.
__global__ __launch_bounds__(256, 4) void k_gemm1_place(const float* __restrict__ xin,
                                                        const unsigned short* __restrict__ wfrag,
                                                        const float* __restrict__ att_s,
                                                        const float* __restrict__ att_d,
                                                        unsigned short* __restrict__ hb,
                                                        float* __restrict__ alpha_s,
                                                        float* __restrict__ alpha_d,
                                                        const int* __restrict__ ei,
                                                        const float* __restrict__ ew,
                                                        int* __restrict__ counter, int cstride,
                                                        int2* __restrict__ csr, int cap){
  if (blockIdx.x >= PLACE_BLOCKS){
    gemm_mfma<false>(blockIdx.x - PLACE_BLOCKS, xin, wfrag, att_s, att_d, hb, alpha_s, alpha_d);
  } else {
    int pb = blockIdx.x;
    int e0 = pb * 1024 + threadIdx.x;
    int ss[4], dd[4], pp[4]; float wwv[4]; bool va[4];
#pragma unroll
    for (int i = 0; i < 4; i++){
      int e = e0 + i * 256;
      va[i] = e < N_EDGES;
      ss[i] = va[i] ? ei[e] : 0;
      dd[i] = va[i] ? ei[N_EDGES + e] : 0;
      wwv[i] = va[i] ? ew[e] : 0.f;
    }
#pragma unroll
    for (int i = 0; i < 4; i++) if (va[i]) pp[i] = atomicAdd(&counter[dd[i] * cstride], 1);
#pragma unroll
    for (int i = 0; i < 4; i++)
      if (va[i] && pp[i] < cap)
        csr[(size_t)dd[i] * cap + pp[i]] = make_int2(ss[i], __float_as_int(wwv[i]));
  }
}

// layer-2 GEMM standalone (fallback path; A input bf16)
__global__ __launch_bounds__(256, 4) void k_gemm_alpha(const unsigned short* __restrict__ xin,
                                                       const unsigned short* __restrict__ wfrag,
                                                       const float* __restrict__ att_s,
                                                       const float* __restrict__ att_d,
                                                       unsigned short* __restrict__ hb,
                                                       float* __restrict__ alpha_s,
                                                       float* __restrict__ alpha_d){
  gemm_mfma<true>(blockIdx.x, xin, wfrag, att_s, att_d, hb, alpha_s, alpha_d);
}

// ---------------- agg core: softmax + aggregation + bias + GELU (+res/LN) ----
// 16 lanes per node. FAST PATH: first 32 slots fused — one dependent
// csr->alpha->exp round, then 32 row gathers with no intervening branch
// (measured-best round-5 form: no __any ballot between chunks, int2 entries,
// epilogue hoisted; VGPR~96 -> ~20% occupancy = measured optimum of the
// occupancy/L2-reuse tradeoff; rounds 7-11 probed occupancy/MLP/order/bytes
// and all regressed or were null).
template<bool LN>
__device__ __forceinline__ void agg_core(const unsigned short* __restrict__ hb,
                                         const float* __restrict__ alpha_s,
                                         const float* __restrict__ alpha_d,
                                         const int* __restrict__ counter, int cstride,
                                         const int2* __restrict__ csr, int cap,
                                         float c,
                                         const float* __restrict__ bias_l,
                                         const float* __restrict__ xres,
                                         const float* __restrict__ gamma,
                                         const float* __restrict__ beta,
                                         int n, int cg, int qbase,
                                         float o[8]){
  int deg = counter[n * cstride];
  int dg = min(deg, cap);
  size_t rs = (size_t)n * cap;
  float ad = alpha_d[n];
  float as_n = alpha_s[n];

  uint4 u_self = *((const uint4*)(hb + (size_t)n * D) + cg);
  float4 b_lo = *(const float4*)(bias_l + cg * 8);
  float4 b_hi = *(const float4*)(bias_l + cg * 8 + 4);
  float4 xr_lo, xr_hi, g_lo, g_hi, bt_lo, bt_hi;
  if constexpr (LN){
    const float* xr = xres + (size_t)n * D + cg * 8;
    xr_lo = *(const float4*)(xr);
    xr_hi = *(const float4*)(xr + 4);
    g_lo  = *(const float4*)(gamma + cg * 8);
    g_hi  = *(const float4*)(gamma + cg * 8 + 4);
    bt_lo = *(const float4*)(beta + cg * 8);
    bt_hi = *(const float4*)(beta + cg * 8 + 4);
  }

  float z = 0.f, wsum = 0.f;
  float acc[8];
#pragma unroll
  for (int k = 0; k < 8; k++) acc[k] = 0.f;

  // ---- fused first-32 fast path ----
  {
    float p = 0.f, p2 = 0.f; int s = n, s2 = n;
    if (cg < dg){
      int2 eg = csr[rs + cg];
      s = eg.x;
      float w = __int_as_float(eg.y);
      wsum += w;
      p = __expf(lrelu(alpha_s[s] + ad + c * w));
    }
    if (16 + cg < dg){
      int2 eg = csr[rs + 16 + cg];
      s2 = eg.x;
      float w = __int_as_float(eg.y);
      wsum += w;
      p2 = __expf(lrelu(alpha_s[s2] + ad + c * w));
    }
    z += p + p2;
#pragma unroll
    for (int i = 0; i < 16; i++){
      float pi = __shfl(p, qbase + i, 64);
      int   si = __shfl(s, qbase + i, 64);
      uint4 u = *((const uint4*)(hb + (size_t)si * D) + cg);
      acc[0] += pi * bf_lo(u.x); acc[1] += pi * bf_hi(u.x);
      acc[2] += pi * bf_lo(u.y); acc[3] += pi * bf_hi(u.y);
      acc[4] += pi * bf_lo(u.z); acc[5] += pi * bf_hi(u.z);
      acc[6] += pi * bf_lo(u.w); acc[7] += pi * bf_hi(u.w);
    }
#pragma unroll
    for (int i = 0; i < 16; i++){
      float pi = __shfl(p2, qbase + i, 64);
      int   si = __shfl(s2, qbase + i, 64);
      uint4 u = *((const uint4*)(hb + (size_t)si * D) + cg);
      acc[0] += pi * bf_lo(u.x); acc[1] += pi * bf_hi(u.x);
      acc[2] += pi * bf_lo(u.y); acc[3] += pi * bf_hi(u.y);
      acc[4] += pi * bf_lo(u.z); acc[5] += pi * bf_hi(u.z);
      acc[6] += pi * bf_lo(u.w); acc[7] += pi * bf_hi(u.w);
    }
  }
  // ---- rare tail (deg > 32) ----
  for (int base = 32; base < dg; base += 16){
    int j = base + cg;
    float p = 0.f; int s = n;
    if (j < dg){
      int2 eg = csr[rs + j];
      s = eg.x;
      float w = __int_as_float(eg.y);
      wsum += w;
      p = __expf(lrelu(alpha_s[s] + ad + c * w));
    }
    z += p;
#pragma unroll
    for (int i = 0; i < 16; i++){
      float pi = __shfl(p, qbase + i, 64);
      int   si = __shfl(s, qbase + i, 64);
      uint4 u = *((const uint4*)(hb + (size_t)si * D) + cg);
      acc[0] += pi * bf_lo(u.x); acc[1] += pi * bf_hi(u.x);
      acc[2] += pi * bf_lo(u.y); acc[3] += pi * bf_hi(u.y);
      acc[4] += pi * bf_lo(u.z); acc[5] += pi * bf_hi(u.z);
      acc[6] += pi * bf_lo(u.w); acc[7] += pi * bf_hi(u.w);
    }
  }
#pragma unroll
  for (int ofs = 8; ofs; ofs >>= 1){
    z += __shfl_xor(z, ofs, 64);
    wsum += __shfl_xor(wsum, ofs, 64);
  }

  float lw = wsum / fmaxf((float)deg, 1.0f);
  float ps = __expf(lrelu(as_n + ad + c * lw));
  z += ps;
  acc[0] += ps * bf_lo(u_self.x); acc[1] += ps * bf_hi(u_self.x);
  acc[2] += ps * bf_lo(u_self.y); acc[3] += ps * bf_hi(u_self.y);
  acc[4] += ps * bf_lo(u_self.z); acc[5] += ps * bf_hi(u_self.z);
  acc[6] += ps * bf_lo(u_self.w); acc[7] += ps * bf_hi(u_self.w);

  float inv = 1.0f / z;
  float bv[8] = {b_lo.x, b_lo.y, b_lo.z, b_lo.w, b_hi.x, b_hi.y, b_hi.z, b_hi.w};
#pragma unroll
  for (int k = 0; k < 8; k++) o[k] = gelu_exact(acc[k] * inv + bv[k]);

  if constexpr (LN){
    float xrv[8] = {xr_lo.x, xr_lo.y, xr_lo.z, xr_lo.w, xr_hi.x, xr_hi.y, xr_hi.z, xr_hi.w};
    float s1 = 0.f;
#pragma unroll
    for (int k = 0; k < 8; k++){ o[k] += xrv[k]; s1 += o[k]; }
#pragma unroll
    for (int ofs = 8; ofs; ofs >>= 1) s1 += __shfl_xor(s1, ofs, 64);
    float mu = s1 * (1.0f / D);
    float s2 = 0.f;
#pragma unroll
    for (int k = 0; k < 8; k++){ o[k] -= mu; s2 += o[k] * o[k]; }
#pragma unroll
    for (int ofs = 8; ofs; ofs >>= 1) s2 += __shfl_xor(s2, ofs, 64);
    float rinv = rsqrtf(s2 * (1.0f / D) + LN_EPS);
    float gv[8]  = {g_lo.x, g_lo.y, g_lo.z, g_lo.w, g_hi.x, g_hi.y, g_hi.z, g_hi.w};
    float btv[8] = {bt_lo.x, bt_lo.y, bt_lo.z, bt_lo.w, bt_hi.x, bt_hi.y, bt_hi.z, bt_hi.w};
#pragma unroll
    for (int k = 0; k < 8; k++) o[k] = o[k] * rinv * gv[k] + btv[k];
  }
}

// ---------------- layer-1 agg + FUSED layer-2 GEMM (16 nodes/block) --------
// After the agg epilogue the block holds the 16x128 bf16 GELU tile -> stage
// to LDS, 4 waves each compute 2 col-tiles of h2 = tile@W2, alpha2 reduced
// via LDS float atomics. Bit-identical numerics to the plain path.
__global__ __launch_bounds__(256) void k_agg1_fused(const unsigned short* __restrict__ hb,
                                                    const float* __restrict__ alpha_s,
                                                    const float* __restrict__ alpha_d,
                                                    const int* __restrict__ counter, int cstride,
                                                    const int2* __restrict__ csr, int cap,
                                                    const float* __restrict__ c_e,
                                                    const float* __restrict__ bias,
                                                    const unsigned short* __restrict__ wfrag2,
                                                    const float* __restrict__ att_s2,
                                                    const float* __restrict__ att_d2,
                                                    unsigned short* __restrict__ hb2,
                                                    float* __restrict__ alpha2_s,
                                                    float* __restrict__ alpha2_d){
  __shared__ __align__(16) unsigned short astage[16 * 136];  // A tile, reused for h2
  __shared__ float apart_s[16], apart_d[16];
  int tid = threadIdx.x;
  int lane = tid & 63;
  int cg = lane & 15;
  int qbase = lane & 48;
  int n = blockIdx.x * 16 + (tid >> 4);

  float o[8];
  agg_core<false>(hb, alpha_s, alpha_d, counter, cstride, csr, cap, c_e[0],
                  bias, nullptr, nullptr, nullptr, n, cg, qbase, o);

  // stage bf16 GELU tile: row = tid>>4 (node), cols cg*8..cg*8+7
  unsigned short ob[8];
#pragma unroll
  for (int k = 0; k < 8; k++) ob[k] = f2bf(o[k]);
  *(uint4*)(astage + (tid >> 4) * 136 + cg * 8) = *(const uint4*)ob;
  if (tid < 16){ apart_s[tid] = 0.f; apart_d[tid] = 0.f; }
  __syncthreads();

  // ---- GEMM phase: wave wv computes col-tiles {2wv, 2wv+1} for all 16 rows
  int wv = tid >> 6;
  int quad = lane >> 4, c15 = lane & 15;
  bf16x8 a[4];
#pragma unroll
  for (int kc = 0; kc < 4; kc++)
    a[kc] = *(const bf16x8*)(astage + c15 * 136 + kc * 32 + quad * 8);

  f32x4 acc2[2];
  float attsv[2], attdv[2];
#pragma unroll
  for (int t = 0; t < 2; t++){
    int ct = wv * 2 + t;
    acc2[t] = (f32x4){0.f, 0.f, 0.f, 0.f};
#pragma unroll
    for (int kc = 0; kc < 4; kc++){
      bf16x8 b = *(const bf16x8*)(wfrag2 + ((size_t)(ct * 4 + kc) * 64 + lane) * 8);
      acc2[t] = __builtin_amdgcn_mfma_f32_16x16x32_bf16(a[kc], b, acc2[t], 0, 0, 0);
    }
    attsv[t] = att_s2[ct * 16 + c15];
    attdv[t] = att_d2[ct * 16 + c15];
  }

  // alpha2 partials (this wave's 2 col-tiles), reduce within 16-lane group
#pragma unroll
  for (int reg = 0; reg < 4; reg++){
    float ps = acc2[0][reg] * attsv[0] + acc2[1][reg] * attsv[1];
    float pd = acc2[0][reg] * attdv[0] + acc2[1][reg] * attdv[1];
#pragma unroll
    for (int ofs = 8; ofs; ofs >>= 1){
      ps += __shfl_xor(ps, ofs, 64);
      pd += __shfl_xor(pd, ofs, 64);
    }
    if (c15 == reg){
      atomicAdd(&apart_s[quad * 4 + reg], ps);
      atomicAdd(&apart_d[quad * 4 + reg], pd);
    }
  }
  __syncthreads();                      // all a[] reads done -> astage reusable

  // stage h2: row = quad*4+reg, col = ct*16+c15
#pragma unroll
  for (int t = 0; t < 2; t++){
    int ct = wv * 2 + t;
#pragma unroll
    for (int reg = 0; reg < 4; reg++)
      astage[(quad * 4 + reg) * 136 + ct * 16 + c15] = f2bf(acc2[t][reg]);
  }
  __syncthreads();

  {
    int row = tid >> 4, ccol = tid & 15;             // 256 uint4 = 16 rows x 16
    int grow = blockIdx.x * 16 + row;
    *(uint4*)(hb2 + (size_t)grow * D + ccol * 8) = *(const uint4*)(astage + row * 136 + ccol * 8);
  }
  if (tid < 16){
    int grow = blockIdx.x * 16 + tid;
    alpha2_s[grow] = apart_s[tid];
    alpha2_d[grow] = apart_d[tid];
  }
}

// layer-1 agg plain (fallback): writes bf16 row that feeds standalone gemm2
__global__ __launch_bounds__(256) void k_agg1_plain(const unsigned short* __restrict__ hb,
                                                    const float* __restrict__ alpha_s,
                                                    const float* __restrict__ alpha_d,
                                                    const int* __restrict__ counter, int cstride,
                                                    const int2* __restrict__ csr, int cap,
                                                    const float* __restrict__ c_e,
                                                    const float* __restrict__ bias,
                                                    unsigned short* __restrict__ outp_bf){
  int tid = threadIdx.x;
  int lane = tid & 63;
  int cg = lane & 15;
  int qbase = lane & 48;
  int n = blockIdx.x * 16 + (tid >> 4);
  float o[8];
  agg_core<false>(hb, alpha_s, alpha_d, counter, cstride, csr, cap, c_e[0],
                  bias, nullptr, nullptr, nullptr, n, cg, qbase, o);
  unsigned short ob[8];
#pragma unroll
  for (int k = 0; k < 8; k++) ob[k] = f2bf(o[k]);
  *(uint4*)(outp_bf + (size_t)n * D + cg * 8) = *(const uint4*)ob;
}

// layer-2 agg: residual + LayerNorm, fp32 out
__global__ __launch_bounds__(256) void k_agg2(const unsigned short* __restrict__ hb,
                                              const float* __restrict__ alpha_s,
                                              const float* __restrict__ alpha_d,
                                              const int* __restrict__ counter, int cstride,
                                              const int2* __restrict__ csr, int cap,
                                              const float* __restrict__ c_e,
                                              const float* __restrict__ bias,
                                              const float* __restrict__ xres,
                                              const float* __restrict__ gamma,
                                              const float* __restrict__ beta,
                                              float* __restrict__ outp){
  int tid = threadIdx.x;
  int lane = tid & 63;
  int cg = lane & 15;
  int qbase = lane & 48;
  int n = blockIdx.x * 16 + (tid >> 4);
  float o[8];
  agg_core<true>(hb, alpha_s, alpha_d, counter, cstride, csr, cap, c_e[1],
                 bias + D, xres, gamma, beta, n, cg, qbase, o);
  float* orow = outp + (size_t)n * D + cg * 8;
  *(float4*)(orow)     = make_float4(o[0], o[1], o[2], o[3]);
  *(float4*)(orow + 4) = make_float4(o[4], o[5], o[6], o[7]);
}

extern "C" void kernel_launch(void* const* d_in, const int* in_sizes, int n_in,
                              void* d_out, int out_size, void* d_ws, size_t ws_size,
                              hipStream_t stream) {
  const float* x     = (const float*)d_in[0];
  const int*   ei    = (const int*)d_in[1];       // [2,E]: src then dst
  const float* ew    = (const float*)d_in[2];
  const float* W     = (const float*)d_in[3];     // [2,128,128]
  const float* att_s = (const float*)d_in[4];
  const float* att_d = (const float*)d_in[5];
  const float* lew   = (const float*)d_in[6];
  const float* ae    = (const float*)d_in[7];
  const float* bias  = (const float*)d_in[8];
  const float* gamma = (const float*)d_in[9];
  const float* beta  = (const float*)d_in[10];
  float* out = (float*)d_out;

  const int N = N_NODES;

  // workspace sizing: counters (padded to 64B/line when space allows) +
  // 4 alpha arrays + c_e + wfrag + csr(N*cap*8) + hb (+ hb2 if fused).
  size_t hbB = (size_t)N * D * 2;
  size_t fixP = ((size_t)(16 * N) + 4 * N + 16) * 4 + 65536;  // padded counters
  size_t fix1 = ((size_t)N + 4 * N + 16) * 4 + 65536;         // stride-1 counters
  int cstride; bool fused; int cap;
  if      (ws_size >= fixP + (size_t)N * 64 * 8 + 2 * hbB){ cstride = 16; fused = true;  cap = 64; }
  else if (ws_size >= fixP + (size_t)N * 48 * 8 + 2 * hbB){ cstride = 16; fused = true;  cap = 48; }
  else if (ws_size >= fix1 + (size_t)N * 64 * 8 + 2 * hbB){ cstride = 1;  fused = true;  cap = 64; }
  else if (ws_size >= fix1 + (size_t)N * 64 * 8 + hbB)    { cstride = 1;  fused = false; cap = 64; }
  else                                                     { cstride = 1;  fused = false; cap = 48; }

  // ---- workspace carve (all offsets 16B-aligned) ----
  int*   counter  = (int*)d_ws;                        // N*cstride
  float* alpha_s  = (float*)(counter + (size_t)N * cstride); // N
  float* alpha_d  = alpha_s + N;                       // N
  float* alpha2_s = alpha_d + N;                       // N
  float* alpha2_d = alpha2_s + N;                      // N
  float* c_e      = alpha2_d + N;                      // 2 (+14 pad)
  unsigned short* wfrag = (unsigned short*)(c_e + 16); // 32768 shorts (64 KB)
  int2*  csr      = (int2*)(wfrag + 32768);            // N*cap {src, weight}
  unsigned short* hb  = (unsigned short*)(csr + (size_t)N * cap); // N*D bf16 (layer-1 h)
  unsigned short* hb2 = hb + (size_t)N * D;            // N*D bf16 (layer-2 h, fused only)

  hipMemsetAsync(counter, 0, (size_t)N * cstride * sizeof(int), stream);
  k_prep<<<16, 256, 0, stream>>>(W, wfrag, lew, ae, c_e);

  // ---- layer-1 GEMM fused with CSR build ----
  k_gemm1_place<<<GEMM_BLOCKS + PLACE_BLOCKS, 256, 0, stream>>>(
      x, wfrag, att_s, att_d, hb, alpha_s, alpha_d, ei, ew, counter, cstride, csr, cap);

  if (fused){
    // layer-1 agg + layer-2 GEMM in one kernel
    k_agg1_fused<<<AGG_BLOCKS, 256, 0, stream>>>(
        hb, alpha_s, alpha_d, counter, cstride, csr, cap, c_e, bias,
        wfrag + 16384, att_s + D, att_d + D, hb2, alpha2_s, alpha2_d);
    k_agg2<<<AGG_BLOCKS, 256, 0, stream>>>(
        hb2, alpha2_s, alpha2_d, counter, cstride, csr, cap, c_e, bias, x, gamma, beta, out);
  } else {
    // fallback: layer-1 bf16 intermediate lives in d_out (consumed before agg2 overwrites)
    unsigned short* h1b = (unsigned short*)d_out;
    k_agg1_plain<<<AGG_BLOCKS, 256, 0, stream>>>(
        hb, alpha_s, alpha_d, counter, cstride, csr, cap, c_e, bias, h1b);
    k_gemm_alpha<<<GEMM_BLOCKS, 256, 0, stream>>>(
        h1b, wfrag + 16384, att_s + D, att_d + D, hb, alpha_s, alpha_d);
    k_agg2<<<AGG_BLOCKS, 256, 0, stream>>>(
        hb, alpha_s, alpha_d, counter, cstride, csr, cap, c_e, bias, x, gamma, beta, out);
  }
}